// Round 1
// baseline (212.349 us; speedup 1.0000x reference)
//
#include <hip/hip_runtime.h>
#include <hip/hip_bf16.h>
#include <stdint.h>

// Problem constants (from reference setup_inputs)
#define BB 64
#define SS 2048
#define DD 6
#define HH 8
#define NCH 512           // chains = B*H
#define CHUNKS 128        // chunks per chain
#define LCH 16            // steps per chunk = SS/CHUNKS

// ---------------- compile-time Cayley sign table (Cl(4,1)) ----------------
struct SignTab { float s[32][32]; };

constexpr int popc5_c(unsigned v) {
    int c = 0;
    for (int i = 0; i < 5; ++i) c += (v >> i) & 1u;
    return c;
}

constexpr SignTab make_signs() {
    SignTab t{};
    for (int a = 0; a < 32; ++a) {
        for (int b = 0; b < 32; ++b) {
            int cnt = 0;
            unsigned aa = ((unsigned)a) >> 1;
            while (aa) { cnt += popc5_c(aa & (unsigned)b); aa >>= 1; }
            if ((a & b) & 16) cnt += 1;   // metric: e5^2 = -1 (bit 4)
            t.s[a][b] = (cnt & 1) ? -1.0f : 1.0f;
        }
    }
    return t;
}

constexpr SignTab SGN = make_signs();

// out = a * b  (geometric product, a is LEFT operand: out_k = sum_i s(i,i^k) a_i b_{i^k})
__device__ __forceinline__ void gp_cl41(const float* __restrict__ a,
                                        const float* __restrict__ b,
                                        float* __restrict__ o) {
#pragma unroll
    for (int k = 0; k < 32; ++k) o[k] = 0.0f;
#pragma unroll
    for (int i = 0; i < 32; ++i) {
#pragma unroll
        for (int k = 0; k < 32; ++k) {
            o[k] = fmaf(SGN.s[i][i ^ k] * a[i], b[i ^ k], o[k]);
        }
    }
}

__device__ __forceinline__ void norm32(float* v) {
    float n0 = 0.f, n1 = 0.f, n2 = 0.f, n3 = 0.f;
#pragma unroll
    for (int k = 0; k < 32; k += 4) {
        n0 = fmaf(v[k+0], v[k+0], n0);
        n1 = fmaf(v[k+1], v[k+1], n1);
        n2 = fmaf(v[k+2], v[k+2], n2);
        n3 = fmaf(v[k+3], v[k+3], n3);
    }
    float n = (n0 + n1) + (n2 + n3);
    float inv = 1.0f / (sqrtf(n) + 1e-8f);
#pragma unroll
    for (int k = 0; k < 32; ++k) v[k] *= inv;
}

__device__ __forceinline__ uint32_t f2bf_rne(float f) {
    uint32_t u = __float_as_uint(f);
    return (u + 0x7FFFu + ((u >> 16) & 1u)) >> 16;
}

// ---------------- K1: per-chunk sequential totals ----------------
// tid = c*512 + b*8 + h ; each thread does LCH sequential GP steps from identity.
__global__ __launch_bounds__(256) void k_chunk_totals(
        const float* __restrict__ x, const float* __restrict__ W_in,
        const float* __restrict__ b_in, float* __restrict__ Tbuf) {
    __shared__ float sW[8][228];   // per h: 192 W + 32 bias, stride 228 (bank-stagger 4h)
    for (int idx = threadIdx.x; idx < 8 * 224; idx += 256) {
        int h = idx / 224, r = idx % 224;
        float v;
        if (r < 192) { int d = r / 32, j = r % 32; v = W_in[d * 256 + h * 32 + j]; }
        else         { int j = r - 192;            v = b_in[h * 32 + j]; }
        sW[h][r] = v;
    }
    __syncthreads();

    int tid = blockIdx.x * 256 + threadIdx.x;
    int c  = tid >> 9;
    int bh = tid & 511;
    int b = bh >> 3, h = bh & 7;

    float p[32];
#pragma unroll
    for (int k = 0; k < 32; ++k) p[k] = 0.f;
    p[0] = 1.f;

    const float* xrow = x + ((size_t)b * SS + (size_t)c * LCH) * DD;
#pragma unroll 1
    for (int r = 0; r < LCH; ++r) {
        float xv[6];
#pragma unroll
        for (int d = 0; d < 6; ++d) xv[d] = xrow[d];
        xrow += 6;
        float dl[32];
#pragma unroll
        for (int j = 0; j < 32; ++j) dl[j] = sW[h][192 + j];
#pragma unroll
        for (int d = 0; d < 6; ++d)
#pragma unroll
            for (int j = 0; j < 32; ++j)
                dl[j] = fmaf(xv[d], sW[h][d * 32 + j], dl[j]);
        dl[0] += 1.0f;

        float o[32];
        gp_cl41(dl, p, o);   // newer delta on the LEFT
        norm32(o);
#pragma unroll
        for (int k = 0; k < 32; ++k) p[k] = o[k];
    }

    float* dst = Tbuf + ((size_t)bh * CHUNKS + c) * 32;
#pragma unroll
    for (int k = 0; k < 32; ++k) dst[k] = p[k];
}

// ---------------- K2: Kogge-Stone scan of chunk totals per chain ----------------
__global__ __launch_bounds__(128) void k_scan_totals(
        const float* __restrict__ Tbuf, float* __restrict__ Ebuf) {
    __shared__ float sT[CHUNKS][33];   // +1 pad to kill bank conflicts
    int chain = blockIdx.x;            // 0..511
    int c = threadIdx.x;               // 0..127

    float v[32];
    const float* src = Tbuf + ((size_t)chain * CHUNKS + c) * 32;
#pragma unroll
    for (int k = 0; k < 32; ++k) { v[k] = src[k]; sT[c][k] = v[k]; }
    __syncthreads();

#pragma unroll 1
    for (int off = 1; off < CHUNKS; off <<= 1) {
        float w[32];
        bool act = (c >= off);
        if (act) {
#pragma unroll
            for (int k = 0; k < 32; ++k) w[k] = sT[c - off][k];
        }
        __syncthreads();
        if (act) {
            float o[32];
            gp_cl41(v, w, o);          // v covers newer range -> left
            norm32(o);
#pragma unroll
            for (int k = 0; k < 32; ++k) { v[k] = o[k]; sT[c][k] = v[k]; }
        }
        __syncthreads();
    }

    // exclusive carries: E_0 = identity, E_{c+1} = inclusive_c
    float* dst = Ebuf + (size_t)chain * CHUNKS * 32;
    if (c == 0) {
#pragma unroll
        for (int k = 0; k < 32; ++k) dst[k] = (k == 0) ? 1.f : 0.f;
    }
    if (c < CHUNKS - 1) {
        float* d2 = dst + (size_t)(c + 1) * 32;
#pragma unroll
        for (int k = 0; k < 32; ++k) d2[k] = v[k];
    }
}

// ---------------- K3: re-run chunks seeded with carry, emit psi (bf16) ----------------
__global__ __launch_bounds__(256) void k_scan_apply(
        const float* __restrict__ x, const float* __restrict__ W_in,
        const float* __restrict__ b_in, const float* __restrict__ Ebuf,
        __hip_bfloat16* __restrict__ psi_buf) {
    __shared__ float sW[8][228];
    for (int idx = threadIdx.x; idx < 8 * 224; idx += 256) {
        int h = idx / 224, r = idx % 224;
        float v;
        if (r < 192) { int d = r / 32, j = r % 32; v = W_in[d * 256 + h * 32 + j]; }
        else         { int j = r - 192;            v = b_in[h * 32 + j]; }
        sW[h][r] = v;
    }
    __syncthreads();

    int tid = blockIdx.x * 256 + threadIdx.x;
    int c  = tid >> 9;
    int bh = tid & 511;
    int b = bh >> 3, h = bh & 7;

    float p[32];
    const float* e = Ebuf + ((size_t)bh * CHUNKS + c) * 32;
#pragma unroll
    for (int k = 0; k < 32; ++k) p[k] = e[k];

    const float* xrow = x + ((size_t)b * SS + (size_t)c * LCH) * DD;
#pragma unroll 1
    for (int r = 0; r < LCH; ++r) {
        float xv[6];
#pragma unroll
        for (int d = 0; d < 6; ++d) xv[d] = xrow[d];
        xrow += 6;
        float dl[32];
#pragma unroll
        for (int j = 0; j < 32; ++j) dl[j] = sW[h][192 + j];
#pragma unroll
        for (int d = 0; d < 6; ++d)
#pragma unroll
            for (int j = 0; j < 32; ++j)
                dl[j] = fmaf(xv[d], sW[h][d * 32 + j], dl[j]);
        dl[0] += 1.0f;

        float o[32];
        gp_cl41(dl, p, o);
        norm32(o);
#pragma unroll
        for (int k = 0; k < 32; ++k) p[k] = o[k];

        // store psi_t as bf16 at (b, t, h, :)
        int t = c * LCH + r;
        __hip_bfloat16* dst = psi_buf + (((size_t)b * SS + t) * HH + h) * 32;
        uint32_t pk[16];
#pragma unroll
        for (int m = 0; m < 16; ++m) {
            uint32_t lo = f2bf_rne(p[2 * m]);
            uint32_t hi = f2bf_rne(p[2 * m + 1]);
            pk[m] = lo | (hi << 16);
        }
        uint4* d4 = (uint4*)dst;   // 64B aligned
#pragma unroll
        for (int m = 0; m < 4; ++m) {
            d4[m] = make_uint4(pk[4*m], pk[4*m+1], pk[4*m+2], pk[4*m+3]);
        }
    }
}

// ---------------- K4: output projection 256->32 + normalize ----------------
__global__ __launch_bounds__(256) void k_proj(
        const __hip_bfloat16* __restrict__ psi_buf, const float* __restrict__ W_out,
        const float* __restrict__ b_out, float* __restrict__ out) {
    __shared__ float sWo[256 * 32];   // 32 KB
    __shared__ float sB[32];
    for (int idx = threadIdx.x; idx < 256 * 32; idx += 256) sWo[idx] = W_out[idx];
    if (threadIdx.x < 32) sB[threadIdx.x] = b_out[threadIdx.x];
    __syncthreads();

    int row = blockIdx.x * 256 + threadIdx.x;   // (b*S + s), 0..131071
    float acc[32];
#pragma unroll
    for (int o = 0; o < 32; ++o) acc[o] = sB[o];

    const uint4* prow = (const uint4*)(psi_buf + (size_t)row * 256);
#pragma unroll 4
    for (int g = 0; g < 32; ++g) {
        uint4 q = prow[g];
        uint32_t wz[4] = { q.x, q.y, q.z, q.w };
#pragma unroll
        for (int m = 0; m < 4; ++m) {
            float f0 = __uint_as_float(wz[m] << 16);
            float f1 = __uint_as_float(wz[m] & 0xFFFF0000u);
            int j = g * 8 + m * 2;
#pragma unroll
            for (int o = 0; o < 32; ++o) acc[o] = fmaf(f0, sWo[j * 32 + o], acc[o]);
#pragma unroll
            for (int o = 0; o < 32; ++o) acc[o] = fmaf(f1, sWo[(j + 1) * 32 + o], acc[o]);
        }
    }

    float n0 = 0.f, n1 = 0.f, n2 = 0.f, n3 = 0.f;
#pragma unroll
    for (int o = 0; o < 32; o += 4) {
        n0 = fmaf(acc[o+0], acc[o+0], n0);
        n1 = fmaf(acc[o+1], acc[o+1], n1);
        n2 = fmaf(acc[o+2], acc[o+2], n2);
        n3 = fmaf(acc[o+3], acc[o+3], n3);
    }
    float inv = 1.0f / (sqrtf((n0 + n1) + (n2 + n3)) + 1e-8f);

    float* orow = out + (size_t)row * 32;
#pragma unroll
    for (int o = 0; o < 32; ++o) orow[o] = acc[o] * inv;
}

// ---------------- launcher ----------------
extern "C" void kernel_launch(void* const* d_in, const int* in_sizes, int n_in,
                              void* d_out, int out_size, void* d_ws, size_t ws_size,
                              hipStream_t stream) {
    const float* x     = (const float*)d_in[0];
    const float* W_in  = (const float*)d_in[1];
    const float* b_in  = (const float*)d_in[2];
    const float* W_out = (const float*)d_in[3];
    const float* b_out = (const float*)d_in[4];
    float* out = (float*)d_out;

    char* ws = (char*)d_ws;
    float* Tbuf = (float*)ws;                                   // 512*128*32*4 = 8 MB
    float* Ebuf = (float*)(ws + (size_t)8 * 1024 * 1024);       // 8 MB
    __hip_bfloat16* psi = (__hip_bfloat16*)(ws + (size_t)16 * 1024 * 1024); // 64 MB

    k_chunk_totals<<<256, 256, 0, stream>>>(x, W_in, b_in, Tbuf);
    k_scan_totals <<<512, 128, 0, stream>>>(Tbuf, Ebuf);
    k_scan_apply  <<<256, 256, 0, stream>>>(x, W_in, b_in, Ebuf, psi);
    k_proj        <<<512, 256, 0, stream>>>(psi, W_out, b_out, out);
}